// Round 11
// baseline (44.219 us; speedup 1.0000x reference)
//
#include <hip/hip_runtime.h>
#include <math.h>

#define D_IN_M      0.1f
#define D_OUT_M     1.0f
#define NBLK        2048
#define NTHR        256
#define SLOT_STRIDE 16          // floats between partial slots (64 B)
#define NGRP        32          // hierarchical counter groups
#define GRP_SZ      (NBLK / NGRP)   // 64 blocks per group

__device__ __forceinline__ float waveReduceSum(float v) {
    #pragma unroll
    for (int off = 32; off > 0; off >>= 1) v += __shfl_xor(v, off, 64);
    return v;
}

// R11: ONE worker dispatch + 132-byte memset, best-measured geometry
// (2048x256 = 32 waves/CU), compiler-scheduled loads (R10 proved forced ILP
// is not the lever). Tail avoids all measured traps:
//  - no __threadfence (R5: device-scope L2 writeback x2048 ~ +90us)
//  - no 2048-deep same-address RMW queue (R4: ~20us) -> 2-level counter,
//    max queue depth 64
//  - counters memset to 0 each launch (R7: modular detection from a
//    poisoned start races)
// Ordering: atomicExch slot (ack by consuming old) -> group inc -> last of
// group (old==63) -> master inc -> last of masters (old==31) -> coherent
// slot reads -> plain store out[0].
__global__ __launch_bounds__(NTHR, 2)
void cae_fused_kernel(const float4* __restrict__ x,
                      const float4* __restrict__ xh,
                      const int*    __restrict__ target,
                      const float*  __restrict__ z_in,
                      const float*  __restrict__ z_out,
                      const float*  __restrict__ center_arr,
                      float* __restrict__ ws,
                      unsigned* __restrict__ l1cnt,   // [NGRP]
                      unsigned* __restrict__ l2cnt,   // [1]
                      float* __restrict__ out,
                      long n4, int B, int C, int L,
                      float invBD, float invB) {
    extern __shared__ float smc[];          // C*L normalized centers
    __shared__ float sred[4];
    __shared__ float sorth;
    __shared__ unsigned is_last;

    const int tid  = threadIdx.x;
    const int wave = tid >> 6;
    const int lane = tid & 63;
    const int epl  = L >> 6;                // 2 for L=128
    const long cpb = 6L * NTHR;             // float4s per block chunk (24 KB)

    // ---- center staging: only blocks that carry tc rows ----
    const int nrowblk = (B + 3) >> 2;
    if (blockIdx.x < (unsigned)nrowblk) {
        for (int c = wave; c < C; c += 4) {
            const float e0 = center_arr[c * L + lane * epl + 0];
            const float e1 = center_arr[c * L + lane * epl + 1];
            const float ss = waveReduceSum(e0 * e0 + e1 * e1);
            const float inv = rsqrtf(ss);
            smc[c * L + lane * epl + 0] = e0 * inv;
            smc[c * L + lane * epl + 1] = e1 * inv;
        }
        if (tid == 0) sorth = 0.f;
        __syncthreads();
    }

    float v = 0.f;   // this thread's scaled contribution

    // ---- MSE: contiguous per-block chunk, 6x-unrolled float4 pairs ----
    {
        float acc = 0.f;
        for (long i0 = (long)blockIdx.x * cpb; i0 < n4; i0 += (long)gridDim.x * cpb) {
            const long i = i0 + tid;
            if (i0 + cpb <= n4) {           // full chunk (always at 4096x3072)
                const float4 a0 = x[i];
                const float4 a1 = x[i + NTHR];
                const float4 a2 = x[i + 2 * NTHR];
                const float4 a3 = x[i + 3 * NTHR];
                const float4 a4 = x[i + 4 * NTHR];
                const float4 a5 = x[i + 5 * NTHR];
                const float4 b0 = xh[i];
                const float4 b1 = xh[i + NTHR];
                const float4 b2 = xh[i + 2 * NTHR];
                const float4 b3 = xh[i + 3 * NTHR];
                const float4 b4 = xh[i + 4 * NTHR];
                const float4 b5 = xh[i + 5 * NTHR];
                float d;
                d = a0.x - b0.x; acc += d * d; d = a0.y - b0.y; acc += d * d;
                d = a0.z - b0.z; acc += d * d; d = a0.w - b0.w; acc += d * d;
                d = a1.x - b1.x; acc += d * d; d = a1.y - b1.y; acc += d * d;
                d = a1.z - b1.z; acc += d * d; d = a1.w - b1.w; acc += d * d;
                d = a2.x - b2.x; acc += d * d; d = a2.y - b2.y; acc += d * d;
                d = a2.z - b2.z; acc += d * d; d = a2.w - b2.w; acc += d * d;
                d = a3.x - b3.x; acc += d * d; d = a3.y - b3.y; acc += d * d;
                d = a3.z - b3.z; acc += d * d; d = a3.w - b3.w; acc += d * d;
                d = a4.x - b4.x; acc += d * d; d = a4.y - b4.y; acc += d * d;
                d = a4.z - b4.z; acc += d * d; d = a4.w - b4.w; acc += d * d;
                d = a5.x - b5.x; acc += d * d; d = a5.y - b5.y; acc += d * d;
                d = a5.z - b5.z; acc += d * d; d = a5.w - b5.w; acc += d * d;
            } else {                        // generic tail
                for (long j = i; j < n4; j += NTHR) {
                    const float4 a = x[j], b = xh[j];
                    float d;
                    d = a.x - b.x; acc += d * d; d = a.y - b.y; acc += d * d;
                    d = a.z - b.z; acc += d * d; d = a.w - b.w; acc += d * d;
                }
            }
        }
        v = acc * invBD;
    }

    // ---- triplet-center + outlier: one wave per row ----
    const int row = blockIdx.x * 4 + wave;
    if (row < B) {
        const float zi0 = z_in[row * L + lane * epl + 0];
        const float zi1 = z_in[row * L + lane * epl + 1];
        const int tgt = target[row];
        float pos = 0.f, neg = INFINITY;
        for (int c = 0; c < C; ++c) {
            const float d0 = zi0 - smc[c * L + lane * epl + 0];
            const float d1 = zi1 - smc[c * L + lane * epl + 1];
            const float d2 = waveReduceSum(d0 * d0 + d1 * d1);
            const float dist = sqrtf(d2);
            if (c == tgt) pos = dist;
            else          neg = fminf(neg, dist);
        }
        const float zo0 = z_out[row * L + lane * epl + 0];
        const float zo1 = z_out[row * L + lane * epl + 1];
        const float zo2 = waveReduceSum(zo0 * zo0 + zo1 * zo1);
        if (lane == 0) {
            const float tc = fmaxf(pos + D_IN_M - neg, 0.f);
            const float ol = fmaxf(D_OUT_M - sqrtf(zo2), 0.f);
            v += (tc + ol) * invB;
        }
    }

    // ---- orthogonality (block 0 only) ----
    if (blockIdx.x == 0) {
        float part = 0.f;
        for (int r = wave; r < C; r += 4) {
            const float ra0 = smc[r * L + lane * epl + 0];
            const float ra1 = smc[r * L + lane * epl + 1];
            for (int cc = 0; cc < C; ++cc) {
                const float d = waveReduceSum(
                    ra0 * smc[cc * L + lane * epl + 0] +
                    ra1 * smc[cc * L + lane * epl + 1]);
                const float t = d - (cc == r ? 1.f : 0.f);
                part += t * t;
            }
        }
        if (lane == 0) atomicAdd(&sorth, part);
    }

    // ---- block reduce -> slot -> hierarchical done-counters ----
    v = waveReduceSum(v);
    if (lane == 0) sred[wave] = v;
    __syncthreads();
    if (tid == 0) {
        float s = sred[0] + sred[1] + sred[2] + sred[3];
        if (blockIdx.x == 0) s += sqrtf(sorth);
        const float old = atomicExch(&ws[(long)blockIdx.x * SLOT_STRIDE], s);
        asm volatile("" :: "v"(old));       // consume -> exch acked first
        unsigned last = 0u;
        const unsigned o1 = atomicAdd(&l1cnt[blockIdx.x >> 6], 1u);
        if (o1 == GRP_SZ - 1u) {            // last of this 64-block group
            const unsigned o2 = atomicAdd(l2cnt, 1u);
            last = (o2 == NGRP - 1u) ? 1u : 0u;   // last group overall
        }
        is_last = last;
    }
    __syncthreads();

    // ---- the true last block reduces all slots ----
    if (is_last) {
        float s = 0.f;
        for (int i = tid; i < NBLK; i += NTHR)
            s += atomicAdd(&ws[(long)i * SLOT_STRIDE], 0.0f);  // coherent read
        s = waveReduceSum(s);
        if (lane == 0) sred[wave] = s;
        __syncthreads();
        if (tid == 0) out[0] = sred[0] + sred[1] + sred[2] + sred[3];
    }
}

extern "C" void kernel_launch(void* const* d_in, const int* in_sizes, int n_in,
                              void* d_out, int out_size, void* d_ws, size_t ws_size,
                              hipStream_t stream) {
    const float* x          = (const float*)d_in[0];
    const float* x_hat      = (const float*)d_in[1];
    const int*   target     = (const int*)d_in[2];
    const float* z_in       = (const float*)d_in[3];
    const float* z_out      = (const float*)d_in[4];
    const float* center_arr = (const float*)d_in[5];
    float* out = (float*)d_out;
    float* ws  = (float*)d_ws;

    const int B = in_sizes[2];
    const int D = in_sizes[0] / B;
    const int L = in_sizes[3] / B;
    const int C = in_sizes[5] / L;
    const long n4 = (long)B * D / 4;

    unsigned* l1cnt = (unsigned*)(ws + (long)NBLK * SLOT_STRIDE);
    unsigned* l2cnt = l1cnt + NGRP;

    // zero the 33 counters (132 B) each launch — stream-ordered, capture-safe
    hipMemsetAsync(l1cnt, 0, (NGRP + 1) * sizeof(unsigned), stream);

    cae_fused_kernel<<<NBLK, NTHR, C * L * sizeof(float), stream>>>(
        (const float4*)x, (const float4*)x_hat, target, z_in, z_out, center_arr,
        ws, l1cnt, l2cnt, out, n4, B, C, L, 1.f / ((float)B * D), 1.f / (float)B);
}

// Round 12
// 38.817 us; speedup vs baseline: 1.1392x; 1.1392x over previous
//
#include <hip/hip_runtime.h>
#include <math.h>

#define D_IN_M      0.1f
#define D_OUT_M     1.0f
#define NBLK        2048
#define NTHR        256
#define SLOT_STRIDE 16          // floats between partial slots (64 B)
#define NGRP        32          // hierarchical counter groups
#define GRP_SZ      (NBLK / NGRP)   // 64 blocks per group
#define L1_STRIDE   16          // uints between L1 counters (64 B): R11 packed
                                // them into 1-2 cache lines -> same-line RMW
                                // serialization == same-address (~20us). Pad.

__device__ __forceinline__ float waveReduceSum(float v) {
    #pragma unroll
    for (int off = 32; off > 0; off >>= 1) v += __shfl_xor(v, off, 64);
    return v;
}

// R12: R11 with ONE change — L1 done-counters padded to separate 64B lines.
__global__ __launch_bounds__(NTHR, 2)
void cae_fused_kernel(const float4* __restrict__ x,
                      const float4* __restrict__ xh,
                      const int*    __restrict__ target,
                      const float*  __restrict__ z_in,
                      const float*  __restrict__ z_out,
                      const float*  __restrict__ center_arr,
                      float* __restrict__ ws,
                      unsigned* __restrict__ l1cnt,   // [NGRP*L1_STRIDE]
                      unsigned* __restrict__ l2cnt,   // [1]
                      float* __restrict__ out,
                      long n4, int B, int C, int L,
                      float invBD, float invB) {
    extern __shared__ float smc[];          // C*L normalized centers
    __shared__ float sred[4];
    __shared__ float sorth;
    __shared__ unsigned is_last;

    const int tid  = threadIdx.x;
    const int wave = tid >> 6;
    const int lane = tid & 63;
    const int epl  = L >> 6;                // 2 for L=128
    const long cpb = 6L * NTHR;             // float4s per block chunk (24 KB)

    // ---- center staging: only blocks that carry tc rows ----
    const int nrowblk = (B + 3) >> 2;
    if (blockIdx.x < (unsigned)nrowblk) {
        for (int c = wave; c < C; c += 4) {
            const float e0 = center_arr[c * L + lane * epl + 0];
            const float e1 = center_arr[c * L + lane * epl + 1];
            const float ss = waveReduceSum(e0 * e0 + e1 * e1);
            const float inv = rsqrtf(ss);
            smc[c * L + lane * epl + 0] = e0 * inv;
            smc[c * L + lane * epl + 1] = e1 * inv;
        }
        if (tid == 0) sorth = 0.f;
        __syncthreads();
    }

    float v = 0.f;   // this thread's scaled contribution

    // ---- MSE: contiguous per-block chunk, 6x-unrolled float4 pairs ----
    {
        float acc = 0.f;
        for (long i0 = (long)blockIdx.x * cpb; i0 < n4; i0 += (long)gridDim.x * cpb) {
            const long i = i0 + tid;
            if (i0 + cpb <= n4) {           // full chunk (always at 4096x3072)
                const float4 a0 = x[i];
                const float4 a1 = x[i + NTHR];
                const float4 a2 = x[i + 2 * NTHR];
                const float4 a3 = x[i + 3 * NTHR];
                const float4 a4 = x[i + 4 * NTHR];
                const float4 a5 = x[i + 5 * NTHR];
                const float4 b0 = xh[i];
                const float4 b1 = xh[i + NTHR];
                const float4 b2 = xh[i + 2 * NTHR];
                const float4 b3 = xh[i + 3 * NTHR];
                const float4 b4 = xh[i + 4 * NTHR];
                const float4 b5 = xh[i + 5 * NTHR];
                float d;
                d = a0.x - b0.x; acc += d * d; d = a0.y - b0.y; acc += d * d;
                d = a0.z - b0.z; acc += d * d; d = a0.w - b0.w; acc += d * d;
                d = a1.x - b1.x; acc += d * d; d = a1.y - b1.y; acc += d * d;
                d = a1.z - b1.z; acc += d * d; d = a1.w - b1.w; acc += d * d;
                d = a2.x - b2.x; acc += d * d; d = a2.y - b2.y; acc += d * d;
                d = a2.z - b2.z; acc += d * d; d = a2.w - b2.w; acc += d * d;
                d = a3.x - b3.x; acc += d * d; d = a3.y - b3.y; acc += d * d;
                d = a3.z - b3.z; acc += d * d; d = a3.w - b3.w; acc += d * d;
                d = a4.x - b4.x; acc += d * d; d = a4.y - b4.y; acc += d * d;
                d = a4.z - b4.z; acc += d * d; d = a4.w - b4.w; acc += d * d;
                d = a5.x - b5.x; acc += d * d; d = a5.y - b5.y; acc += d * d;
                d = a5.z - b5.z; acc += d * d; d = a5.w - b5.w; acc += d * d;
            } else {                        // generic tail
                for (long j = i; j < n4; j += NTHR) {
                    const float4 a = x[j], b = xh[j];
                    float d;
                    d = a.x - b.x; acc += d * d; d = a.y - b.y; acc += d * d;
                    d = a.z - b.z; acc += d * d; d = a.w - b.w; acc += d * d;
                }
            }
        }
        v = acc * invBD;
    }

    // ---- triplet-center + outlier: one wave per row ----
    const int row = blockIdx.x * 4 + wave;
    if (row < B) {
        const float zi0 = z_in[row * L + lane * epl + 0];
        const float zi1 = z_in[row * L + lane * epl + 1];
        const int tgt = target[row];
        float pos = 0.f, neg = INFINITY;
        for (int c = 0; c < C; ++c) {
            const float d0 = zi0 - smc[c * L + lane * epl + 0];
            const float d1 = zi1 - smc[c * L + lane * epl + 1];
            const float d2 = waveReduceSum(d0 * d0 + d1 * d1);
            const float dist = sqrtf(d2);
            if (c == tgt) pos = dist;
            else          neg = fminf(neg, dist);
        }
        const float zo0 = z_out[row * L + lane * epl + 0];
        const float zo1 = z_out[row * L + lane * epl + 1];
        const float zo2 = waveReduceSum(zo0 * zo0 + zo1 * zo1);
        if (lane == 0) {
            const float tc = fmaxf(pos + D_IN_M - neg, 0.f);
            const float ol = fmaxf(D_OUT_M - sqrtf(zo2), 0.f);
            v += (tc + ol) * invB;
        }
    }

    // ---- orthogonality (block 0 only) ----
    if (blockIdx.x == 0) {
        float part = 0.f;
        for (int r = wave; r < C; r += 4) {
            const float ra0 = smc[r * L + lane * epl + 0];
            const float ra1 = smc[r * L + lane * epl + 1];
            for (int cc = 0; cc < C; ++cc) {
                const float d = waveReduceSum(
                    ra0 * smc[cc * L + lane * epl + 0] +
                    ra1 * smc[cc * L + lane * epl + 1]);
                const float t = d - (cc == r ? 1.f : 0.f);
                part += t * t;
            }
        }
        if (lane == 0) atomicAdd(&sorth, part);
    }

    // ---- block reduce -> slot -> hierarchical PADDED done-counters ----
    v = waveReduceSum(v);
    if (lane == 0) sred[wave] = v;
    __syncthreads();
    if (tid == 0) {
        float s = sred[0] + sred[1] + sred[2] + sred[3];
        if (blockIdx.x == 0) s += sqrtf(sorth);
        const float old = atomicExch(&ws[(long)blockIdx.x * SLOT_STRIDE], s);
        asm volatile("" :: "v"(old));       // consume -> exch acked first
        unsigned last = 0u;
        const unsigned o1 = atomicAdd(&l1cnt[(blockIdx.x >> 6) * L1_STRIDE], 1u);
        if (o1 == GRP_SZ - 1u) {            // last of this 64-block group
            const unsigned o2 = atomicAdd(l2cnt, 1u);
            last = (o2 == NGRP - 1u) ? 1u : 0u;   // last group overall
        }
        is_last = last;
    }
    __syncthreads();

    // ---- the true last block reduces all slots ----
    if (is_last) {
        float s = 0.f;
        for (int i = tid; i < NBLK; i += NTHR)
            s += atomicAdd(&ws[(long)i * SLOT_STRIDE], 0.0f);  // coherent read
        s = waveReduceSum(s);
        if (lane == 0) sred[wave] = s;
        __syncthreads();
        if (tid == 0) out[0] = sred[0] + sred[1] + sred[2] + sred[3];
    }
}

extern "C" void kernel_launch(void* const* d_in, const int* in_sizes, int n_in,
                              void* d_out, int out_size, void* d_ws, size_t ws_size,
                              hipStream_t stream) {
    const float* x          = (const float*)d_in[0];
    const float* x_hat      = (const float*)d_in[1];
    const int*   target     = (const int*)d_in[2];
    const float* z_in       = (const float*)d_in[3];
    const float* z_out      = (const float*)d_in[4];
    const float* center_arr = (const float*)d_in[5];
    float* out = (float*)d_out;
    float* ws  = (float*)d_ws;

    const int B = in_sizes[2];
    const int D = in_sizes[0] / B;
    const int L = in_sizes[3] / B;
    const int C = in_sizes[5] / L;
    const long n4 = (long)B * D / 4;

    unsigned* l1cnt = (unsigned*)(ws + (long)NBLK * SLOT_STRIDE);
    unsigned* l2cnt = l1cnt + NGRP * L1_STRIDE;

    // zero all padded counters (32*64B + 4B) each launch — capture-safe
    hipMemsetAsync(l1cnt, 0, (NGRP * L1_STRIDE + 1) * sizeof(unsigned), stream);

    cae_fused_kernel<<<NBLK, NTHR, C * L * sizeof(float), stream>>>(
        (const float4*)x, (const float4*)x_hat, target, z_in, z_out, center_arr,
        ws, l1cnt, l2cnt, out, n4, B, C, L, 1.f / ((float)B * D), 1.f / (float)B);
}